// Round 2
// baseline (694.185 us; speedup 1.0000x reference)
//
#include <hip/hip_runtime.h>
#include <math.h>

// LeCun LCN, fused single kernel (correct two-stage formulation).
// x: [32,512,512,3] f32, mask: [32,512,512,1] f32, out: [32,512,512,3] f32.
//
// mean     = gauss19x19 * x          (separable, zero-pad SAME)
// centered = x - mean                (pointwise, image domain)
// var      = gauss19x19 * centered^2 (zero-pad SAME -- pads contribute 0)
// out      = centered / (sqrt(var) + 1e-4) * mask
//
// Tile: 32x32 spatial (96 flat cols), 256 threads, 4 LDS phases:
//  P1: hblur(x)            -> s1[68][152]   rows h0-18..h0+49, flat g0..g0+151
//  P2: vblur(s1)=mean; signed centered^2 -> b2[50][152]  rows h0-9..h0+40
//  P3: hblur(|b2|)         -> hc (= s1 reuse) [50][96]   tile cols only
//  P4: vblur(hc)=var; epilogue (centered recovered from b2 sign trick)

#define TW 32
#define TH 32
#define FC 96            // flat cols in tile
#define S1ROWS 68        // TH + 36
#define SSTR 152         // row stride for s1/b2 (150 used + 2 slop)
#define B2ROWS 50        // TH + 18

__global__ __launch_bounds__(256, 2)
void lecun_lcn_kernel(const float* __restrict__ x,
                      const float* __restrict__ mask,
                      float* __restrict__ out)
{
    __shared__ float s1[S1ROWS * SSTR];   // 41,344 B
    __shared__ float b2[B2ROWS * SSTR];   // 30,400 B

    const int tid = threadIdx.x;
    const int w0  = blockIdx.x * TW;
    const int h0  = blockIdx.y * TH;
    const int b   = blockIdx.z;
    const int g0  = 3 * w0 - 27;          // flat col of rel index 0

    // 1D normalized Gaussian: K[d] = exp(-d^2/2) / 2.5066282880428826
    const float K[10] = {
        3.9894227826685783e-01f,
        2.4197072436877680e-01f,
        5.3990966513188100e-02f,
        4.4318484119380000e-03f,
        1.3383022576489000e-04f,
        1.4867195147343000e-06f,
        6.0758835624000000e-09f,
        9.1347548138000000e-12f,
        5.0522710835000000e-15f,
        1.0279773571669000e-18f
    };

    const float* xb = x + (size_t)b * 512 * 1536;

    // ---------------- Phase 1: hblur(x) -> s1 -------------------------------
    for (int task = tid; task < S1ROWS * 19; task += 256) {
        const int r   = task / 19;
        const int run = task - r * 19;
        const int o0  = run * 8;            // rel col of first of 8 outputs
        const int h   = h0 - 18 + r;
        float* dst = &s1[r * SSTR + o0];
        if ((unsigned)h >= 512u) {
            float4 z = make_float4(0.f, 0.f, 0.f, 0.f);
            ((float4*)dst)[0] = z; ((float4*)dst)[1] = z;
            continue;
        }
        const float* xrow = xb + (size_t)h * 1536;
        const int wsS = g0 + o0 - 29;       // window start, %4 == 0
        float w[64];
        if (wsS >= 0 && wsS + 64 <= 1536) {
            const float4* p = (const float4*)(xrow + wsS);
            #pragma unroll
            for (int q = 0; q < 16; ++q) {
                float4 v = p[q];
                w[4*q+0] = v.x; w[4*q+1] = v.y; w[4*q+2] = v.z; w[4*q+3] = v.w;
            }
        } else {
            #pragma unroll
            for (int i = 0; i < 64; ++i) {
                int j = wsS + i;
                w[i] = ((unsigned)j < 1536u) ? xrow[j] : 0.0f;
            }
        }
        float v1[8];
        #pragma unroll
        for (int i = 0; i < 8; ++i) {
            const int ci = 29 + i;          // center of output i in window
            float a = K[0] * w[ci];
            #pragma unroll
            for (int d = 1; d <= 9; ++d)
                a = fmaf(K[d], w[ci - 3*d] + w[ci + 3*d], a);
            v1[i] = a;
        }
        ((float4*)dst)[0] = make_float4(v1[0], v1[1], v1[2], v1[3]);
        ((float4*)dst)[1] = make_float4(v1[4], v1[5], v1[6], v1[7]);
    }
    __syncthreads();

    // ------- Phase 2: vblur(s1)=mean; signed centered^2 -> b2 ---------------
    for (int task = tid; task < 2 * SSTR; task += 256) {
        const int c   = task % SSTR;
        const int seg = task / SSTR;        // 0: rows 0..24, 1: rows 25..49
        const int r0  = seg * 25;
        const int gc  = g0 + c;
        const bool cin = (unsigned)gc < 1536u;
        float w[19];
        #pragma unroll
        for (int i = 0; i < 19; ++i) w[i] = s1[(r0 + i) * SSTR + c];
        #pragma unroll
        for (int rr = 0; rr < 25; ++rr) {
            float mean = K[0] * w[(rr + 9) % 19];
            #pragma unroll
            for (int d = 0; d < 9; ++d)
                mean = fmaf(K[9 - d], w[(rr + d) % 19] + w[(rr + 18 - d) % 19], mean);
            const int r = r0 + rr;          // b2 row (image row h0-9+r)
            const int h = h0 - 9 + r;
            float c2s = 0.0f;
            if (cin && (unsigned)h < 512u) {
                const float xv = xb[(size_t)h * 1536 + gc];
                const float ce = xv - mean;
                c2s = ce * fabsf(ce);       // signed square
            }
            b2[r * SSTR + c] = c2s;
            if (rr < 24) w[rr % 19] = s1[(r0 + 19 + rr) * SSTR + c];
        }
    }
    __syncthreads();

    // ---------------- Phase 3: hblur(|b2|) -> hc (reuse s1) -----------------
    float* hc = s1;                         // 50 x 96, stride FC
    for (int task = tid; task < B2ROWS * 12; task += 256) {
        const int r   = task / 12;
        const int run = task - r * 12;
        const int o0  = run * 8;            // tile flat col of first output
        float w[64];
        const float4* p = (const float4*)&b2[r * SSTR + o0];
        #pragma unroll
        for (int q = 0; q < 16; ++q) {
            float4 v = p[q];
            w[4*q+0] = fabsf(v.x); w[4*q+1] = fabsf(v.y);
            w[4*q+2] = fabsf(v.z); w[4*q+3] = fabsf(v.w);
        }
        float v1[8];
        #pragma unroll
        for (int i = 0; i < 8; ++i) {
            const int ci = 27 + i;          // center: rel = o0 + i + 27
            float a = K[0] * w[ci];
            #pragma unroll
            for (int d = 1; d <= 9; ++d)
                a = fmaf(K[d], w[ci - 3*d] + w[ci + 3*d], a);
            v1[i] = a;
        }
        float4* dst = (float4*)&hc[r * FC + o0];
        dst[0] = make_float4(v1[0], v1[1], v1[2], v1[3]);
        dst[1] = make_float4(v1[4], v1[5], v1[6], v1[7]);
    }
    __syncthreads();

    // ---------------- Phase 4: vblur(hc)=var; epilogue ----------------------
    if (tid < 192) {
        const int c   = tid % FC;           // tile flat col
        const int seg = tid / FC;           // rows seg*16 .. +16
        const int r0  = seg * 16;
        const int cw  = c / 3;
        const int gc  = 3 * w0 + c;
        float w[19];
        #pragma unroll
        for (int i = 0; i < 19; ++i) w[i] = hc[(r0 + i) * FC + c];
        #pragma unroll
        for (int rr = 0; rr < 16; ++rr) {
            float var = K[0] * w[(rr + 9) % 19];
            #pragma unroll
            for (int d = 0; d < 9; ++d)
                var = fmaf(K[9 - d], w[(rr + d) % 19] + w[(rr + 18 - d) % 19], var);
            const int h = h0 + r0 + rr;
            const size_t rowoff = (size_t)(b * 512 + h);
            const float sc2 = b2[(r0 + rr + 9) * SSTR + (c + 27)];
            const float ce  = copysignf(sqrtf(fabsf(sc2)), sc2);
            const float stdv = sqrtf(var) + 1e-4f;
            const float mv  = mask[rowoff * 512 + w0 + cw];
            out[rowoff * 1536 + gc] = ce * __builtin_amdgcn_rcpf(stdv) * mv;
            if (rr < 15) w[rr % 19] = hc[(r0 + 19 + rr) * FC + c];
        }
    }
}

extern "C" void kernel_launch(void* const* d_in, const int* in_sizes, int n_in,
                              void* d_out, int out_size, void* d_ws, size_t ws_size,
                              hipStream_t stream) {
    const float* x0   = (const float*)d_in[0];
    const float* mask = (const float*)d_in[1];
    float* out = (float*)d_out;

    dim3 grid(512 / TW, 512 / TH, 32);   // (16, 16, 32) = 8192 blocks
    dim3 block(256);
    lecun_lcn_kernel<<<grid, block, 0, stream>>>(x0, mask, out);
}

// Round 3
// 371.325 us; speedup vs baseline: 1.8695x; 1.8695x over previous
//
#include <hip/hip_runtime.h>
#include <math.h>

// LeCun LCN, fused single kernel, radius-5 truncated Gaussian (taps d>=6 have
// total weight 1.2e-8 -- numerically invisible vs the 4.9e-2 threshold).
//
// mean     = gauss11x11 * x          (separable, zero-pad SAME)
// centered = x - mean
// var      = gauss11x11 * centered^2 (zero-pad SAME)
// out      = centered / (sqrt(var) + 1e-4) * mask
//
// Tile 32x32 (96 flat cols), 256 threads, LDS 48.1 KB -> 3 blocks/CU:
//  P1: hblur(x)        -> s1[52][128]  rows h0-10..h0+41, flat cols fc0..fc0+125
//  P2: vblur(s1)=mean; centered -> b2[42][128]  rows h0-5..h0+36
//  P3: hblur(b2^2)     -> hc (reuse s1) [42][96]
//  P4: vblur(hc)=var; epilogue, float4 stores
// Vertical phases: thread-per-(row, float4-group), 11 aligned ds_read_b128,
// 4 independent accumulator chains per thread.

#define TW 32
#define TH 32
#define FC 96            // 3*TW
#define S1W 128          // LDS row stride (126 cols used + 2 slop)
#define S1R 52           // TH + 20
#define B2R 42           // TH + 10
#define HCW 96           // hc row stride

__global__ __launch_bounds__(256, 3)
void lecun_lcn_kernel(const float* __restrict__ x,
                      const float* __restrict__ mask,
                      float* __restrict__ out)
{
    __shared__ float s1[S1R * S1W];   // 26,624 B
    __shared__ float b2[B2R * S1W];   // 21,504 B

    const int tid = threadIdx.x;
    const int w0  = blockIdx.x * TW;
    const int h0  = blockIdx.y * TH;
    const int bi  = blockIdx.z;
    const int fc0 = 3 * w0 - 15;      // flat col of s1/b2 index 0

    // 1D Gaussian (std=1), taps 0..5, normalized by the full 19-tap sum.
    const float K[6] = {
        3.9894227826685783e-01f,
        2.4197072322439816e-01f,
        5.3990966224238430e-02f,
        4.4318483882270000e-03f,
        1.3383022504889000e-04f,
        1.4867195067806000e-06f
    };

    const float* xb = x + (size_t)bi * 512 * 1536;

    // ---------------- Phase 1: hblur(x) -> s1 -------------------------------
    // task -> (row r of 52, run of 8 cols; 16 runs cover 128 cols)
    for (int t = tid; t < S1R * 16; t += 256) {
        const int r   = t >> 4;
        const int run = t & 15;
        const int h   = h0 - 10 + r;
        float* dst = &s1[r * S1W + run * 8];
        if ((unsigned)h >= 512u) {
            float4 z = make_float4(0.f, 0.f, 0.f, 0.f);
            ((float4*)dst)[0] = z; ((float4*)dst)[1] = z;
            continue;
        }
        const float* xrow = xb + (size_t)h * 1536;
        const int gc0 = fc0 + run * 8;     // first output flat col
        const int a   = gc0 - 17;          // window start, (gc0-15)%4==2 -> a%4==0
        float w[40];                       // covers [gc0-15, gc0+22] at w[2..39]
        if (a >= 0 && a <= 1536 - 40) {
            const float4* p = (const float4*)(xrow + a);
            #pragma unroll
            for (int q = 0; q < 10; ++q) {
                float4 v = p[q];
                w[4*q+0] = v.x; w[4*q+1] = v.y; w[4*q+2] = v.z; w[4*q+3] = v.w;
            }
        } else {
            #pragma unroll
            for (int i = 0; i < 40; ++i) {
                int j = a + i;
                w[i] = ((unsigned)j < 1536u) ? xrow[j] : 0.0f;
            }
        }
        float v1[8];
        #pragma unroll
        for (int i = 0; i < 8; ++i) {
            const int ci = 17 + i;
            float acc = K[0] * w[ci];
            #pragma unroll
            for (int d = 1; d <= 5; ++d)
                acc = fmaf(K[d], w[ci - 3*d] + w[ci + 3*d], acc);
            v1[i] = acc;
        }
        ((float4*)dst)[0] = make_float4(v1[0], v1[1], v1[2], v1[3]);
        ((float4*)dst)[1] = make_float4(v1[4], v1[5], v1[6], v1[7]);
    }
    __syncthreads();

    // ------- Phase 2: vblur(s1)=mean; centered = x - mean -> b2 -------------
    // task -> (row r of 42, float4-group g4 of 32)
    for (int t = tid; t < B2R * 32; t += 256) {
        const int r  = t >> 5;
        const int c4 = (t & 31) * 4;
        const int h  = h0 - 5 + r;
        float4* dst = (float4*)&b2[r * S1W + c4];
        if ((unsigned)h >= 512u) {
            *dst = make_float4(0.f, 0.f, 0.f, 0.f);
            continue;
        }
        float4 v = *(const float4*)&s1[(r + 5) * S1W + c4];
        float m0 = K[0] * v.x, m1 = K[0] * v.y, m2 = K[0] * v.z, m3 = K[0] * v.w;
        #pragma unroll
        for (int d = 1; d <= 5; ++d) {
            float4 aa = *(const float4*)&s1[(r + 5 - d) * S1W + c4];
            float4 bb = *(const float4*)&s1[(r + 5 + d) * S1W + c4];
            m0 = fmaf(K[d], aa.x + bb.x, m0);
            m1 = fmaf(K[d], aa.y + bb.y, m1);
            m2 = fmaf(K[d], aa.z + bb.z, m2);
            m3 = fmaf(K[d], aa.w + bb.w, m3);
        }
        const float* xrow = xb + (size_t)h * 1536;
        const int gcb = fc0 + c4;
        float x0v = ((unsigned)(gcb + 0) < 1536u) ? xrow[gcb + 0] : 0.0f;
        float x1v = ((unsigned)(gcb + 1) < 1536u) ? xrow[gcb + 1] : 0.0f;
        float x2v = ((unsigned)(gcb + 2) < 1536u) ? xrow[gcb + 2] : 0.0f;
        float x3v = ((unsigned)(gcb + 3) < 1536u) ? xrow[gcb + 3] : 0.0f;
        // out-of-image cols must be exact 0 (zero-pad of second conv)
        float c0 = ((unsigned)(gcb + 0) < 1536u) ? (x0v - m0) : 0.0f;
        float c1 = ((unsigned)(gcb + 1) < 1536u) ? (x1v - m1) : 0.0f;
        float c2 = ((unsigned)(gcb + 2) < 1536u) ? (x2v - m2) : 0.0f;
        float c3 = ((unsigned)(gcb + 3) < 1536u) ? (x3v - m3) : 0.0f;
        *dst = make_float4(c0, c1, c2, c3);
    }
    __syncthreads();

    // ---------------- Phase 3: hblur(b2^2) -> hc (reuse s1) -----------------
    float* hc = s1;                        // 42 x 96
    for (int t = tid; t < B2R * 12; t += 256) {
        const int r   = t / 12;
        const int run = t - r * 12;
        const int tc0 = run * 8;           // tile flat col of first output
        float w[40];                       // b2 idx [tc0, tc0+40)
        const float4* p = (const float4*)&b2[r * S1W + tc0];
        #pragma unroll
        for (int q = 0; q < 10; ++q) {
            float4 v = p[q];
            w[4*q+0] = v.x * v.x; w[4*q+1] = v.y * v.y;
            w[4*q+2] = v.z * v.z; w[4*q+3] = v.w * v.w;
        }
        float v1[8];
        #pragma unroll
        for (int i = 0; i < 8; ++i) {
            const int ci = 15 + i;         // center: b2 idx = tc0+i+15
            float acc = K[0] * w[ci];
            #pragma unroll
            for (int d = 1; d <= 5; ++d)
                acc = fmaf(K[d], w[ci - 3*d] + w[ci + 3*d], acc);
            v1[i] = acc;
        }
        float4* dst = (float4*)&hc[r * HCW + tc0];
        dst[0] = make_float4(v1[0], v1[1], v1[2], v1[3]);
        dst[1] = make_float4(v1[4], v1[5], v1[6], v1[7]);
    }
    __syncthreads();

    // ---------------- Phase 4: vblur(hc)=var; epilogue ----------------------
    // task -> (row r of 32, float4-group g4 of 24)
    for (int t = tid; t < TH * 24; t += 256) {
        const int r  = t / 24;
        const int tc = (t - r * 24) * 4;
        float4 v = *(const float4*)&hc[(r + 5) * HCW + tc];
        float s0 = K[0] * v.x, s1v = K[0] * v.y, s2v = K[0] * v.z, s3 = K[0] * v.w;
        #pragma unroll
        for (int d = 1; d <= 5; ++d) {
            float4 aa = *(const float4*)&hc[(r + 5 - d) * HCW + tc];
            float4 bb = *(const float4*)&hc[(r + 5 + d) * HCW + tc];
            s0  = fmaf(K[d], aa.x + bb.x, s0);
            s1v = fmaf(K[d], aa.y + bb.y, s1v);
            s2v = fmaf(K[d], aa.z + bb.z, s2v);
            s3  = fmaf(K[d], aa.w + bb.w, s3);
        }
        const int h = h0 + r;
        const size_t rowoff = (size_t)(bi * 512 + h);
        // centered from b2 (row r+5, col idx tc+15+j) -- misaligned, b32 reads
        const float* bp = &b2[(r + 5) * S1W + tc + 15];
        float c0 = bp[0], c1 = bp[1], c2 = bp[2], c3 = bp[3];
        const float* mrow = mask + rowoff * 512 + w0;
        float mv0 = mrow[(tc + 0) / 3];
        float mv1 = mrow[(tc + 1) / 3];
        float mv2 = mrow[(tc + 2) / 3];
        float mv3 = mrow[(tc + 3) / 3];
        float4 o;
        o.x = c0 * __builtin_amdgcn_rcpf(sqrtf(s0)  + 1e-4f) * mv0;
        o.y = c1 * __builtin_amdgcn_rcpf(sqrtf(s1v) + 1e-4f) * mv1;
        o.z = c2 * __builtin_amdgcn_rcpf(sqrtf(s2v) + 1e-4f) * mv2;
        o.w = c3 * __builtin_amdgcn_rcpf(sqrtf(s3)  + 1e-4f) * mv3;
        *(float4*)&out[rowoff * 1536 + 3 * w0 + tc] = o;
    }
}

extern "C" void kernel_launch(void* const* d_in, const int* in_sizes, int n_in,
                              void* d_out, int out_size, void* d_ws, size_t ws_size,
                              hipStream_t stream) {
    const float* x0   = (const float*)d_in[0];
    const float* mask = (const float*)d_in[1];
    float* out = (float*)d_out;

    dim3 grid(512 / TW, 512 / TH, 32);   // (16, 16, 32) = 8192 blocks
    dim3 block(256);
    lecun_lcn_kernel<<<grid, block, 0, stream>>>(x0, mask, out);
}